// Round 3
// baseline (241.695 us; speedup 1.0000x reference)
//
#include <hip/hip_runtime.h>
#include <stdint.h>

// GradientLoss: sum_c mean( (conv3d_c(x) - conv3d_c(y))^2 ), c in {d,h,w} Sobel dirs.
// conv linear -> conv(x)-conv(y) = conv(x-y). Separable: s=[1,2,1], g=[1,0,-1];
// SAME zero pad; squared output -> flip irrelevant.
//
// R12: ABANDON global_load_lds -> T14 reg-staged split (load->VGPR, ds_write).
//  - R9/R10/R11 post-mortem: DMA depth 2, more blocks, DMA depth 3 ALL land at
//    45-52 us with VALU~22%, HBM~21%, Occ~16%. Per-iter cadence ~7000cy vs
//    ~1000cy compute -> the LDS-DMA path serializes regardless of vmcnt depth.
//  - New schedule per iter (ONE __syncthreads, drains vmcnt+lgkm exactly where
//    needed): sync -> ds_write buf[(it+1)&1] (regs loaded last iter) -> issue
//    plain float4 loads for next plane -> compute from buf[it&1].
//    Loads have a full iteration of slack, consumed by the WRITE not the read;
//    ds_read ordering comes from __syncthreads lgkm drain. No DMA aliasing.
//  - 2-buffer ping-pong: LDS 72KB -> 35.9KB -> 4 blocks/CU = 16 waves/CU
//    (2x the TLP of any DMA variant). Staging = 20 VGPR (5 x float4).
//  - TD=16: d-halo 18/16, grid 480 blocks, all resident in one round.
// Kept: 56-lane packed rows (896 B), clamped-index uniform staging (overshoot
// harmless, masked by pm), intra-block 4-wave sharing, butterfly reduction.

#define N_  2
#define D_  160
#define H_  192
#define W_  224
#define PS  (H_ * W_)

#define TD  16                 // d-planes computed per block (160/16 = 10 chunks)
#define TH  8                  // h output rows per block (2 per wave)
constexpr int SROWS = TH + 2;  // 10 staged rows per plane
constexpr int ROWF  = 224;     // floats per packed LDS row (= W, 896 B)
constexpr float SCALE = 1.0f / ((float)N_ * D_ * H_ * W_);

__global__ __launch_bounds__(256, 4)
void grad_loss_kernel(const float* __restrict__ x, const float* __restrict__ y,
                      float* __restrict__ out) {
    __shared__ float sbuf[2][SROWS][2][ROWF];  // ping-pong: 2 x 10 rows x {x,y} x 896B
    __shared__ float wsum[4];

    const int tid  = threadIdx.x;
    const int lane = tid & 63;
    const int wv   = tid >> 6;

    const int h0 = blockIdx.y * TH;
    const int nchunks = D_ / TD;               // 10
    const int nb = blockIdx.z / nchunks;
    const int d0 = (blockIdx.z % nchunks) * TD;

    const float* vbx = x + (size_t)nb * ((size_t)D_ * PS);
    const float* vby = y + (size_t)nb * ((size_t)D_ * PS);

    // ---- 5 staging items per wave: item = (row l, array a); 20 items/block ----
    int sl[5], sa[5], srw[5];
    const float* sb[5];
    #pragma unroll
    for (int k = 0; k < 5; ++k) {
        int item = 5 * wv + k;                 // 20 items over 4 waves
        sl[k] = item >> 1;
        sa[k] = item & 1;
        int ghc = min(max(h0 - 1 + sl[k], 0), H_ - 1);  // clamp; zeroed on read
        srw[k] = ghc * W_;
        sb[k]  = sa[k] ? vby : vbx;
    }
    const int lo4 = lane * 4;                  // float offset in row (16B/lane)
    const bool sact = lane < 56;               // 56 lanes x 16B = 896B = one row

    float4 rg[5];                              // in-flight plane (reg staging)

    auto rload = [&](int p) {                  // plain vectorized global loads
        int pc = min(max(p, 0), D_ - 1);       // clamp; masked via pm on read
        size_t poff = (size_t)pc * PS;
        if (sact) {
            #pragma unroll
            for (int k = 0; k < 5; ++k)
                rg[k] = *(const float4*)(sb[k] + poff + srw[k] + lo4);
        }
    };
    auto swrite = [&](int bsel) {              // regs -> LDS (ds_write_b128)
        if (sact) {
            #pragma unroll
            for (int k = 0; k < 5; ++k)
                *(float4*)&sbuf[bsel][sl[k]][sa[k]][lo4] = rg[k];
        }
    };

    // ---- compute-side masks ----
    const bool wact = lane < 56;
    float rmask[4];
    #pragma unroll
    for (int r = 0; r < 4; ++r) {              // wave reads staged rows 2wv..2wv+3
        int gh = h0 - 1 + 2 * wv + r;
        rmask[r] = (((unsigned)gh < (unsigned)H_) && wact) ? 1.f : 0.f;
    }
    const int lrd = (lane < 56 ? lane : 55) * 4;  // clamped LDS read offset

    float4 A0[2], A1[2], A2[2], B0[2], B1[2], B2[2];   // d-history (p-2, p-1)
    const float4 z4 = make_float4(0.f, 0.f, 0.f, 0.f);
    #pragma unroll
    for (int j = 0; j < 2; ++j) { A0[j]=A1[j]=A2[j]=B0[j]=B1[j]=B2[j]=z4; }
    float acc = 0.f;

    // ---- prologue: plane d0-1 -> buf0; plane d0 in regs ----
    rload(d0 - 1);
    swrite(0);
    rload(d0);

    for (int it = 0; it < TD + 2; ++it) {
        // Orders: (a) prev iter's ds_writes visible to all waves before reads;
        // (b) prev iter's reads of buf[(it+1)&1] done before we overwrite it;
        // (c) drains vmcnt for rg (loaded a full iteration ago).
        __syncthreads();

        swrite((it + 1) & 1);                  // plane d0+it -> other buffer
        rload(d0 + 1 + it);                    // next plane -> regs (1-iter slack)

        const int q = d0 - 1 + it;             // plane processed this iter
        const float pm = (q >= 0 && q < D_) ? 1.f : 0.f;
        const int bsel = it & 1;

        // ---- in-plane stencils from LDS (float4 + 2 shuffles per row) ----
        float4 sw[4], gw[4];
        #pragma unroll
        for (int r = 0; r < 4; ++r) {
            const int l = 2 * wv + r;
            const float4 xr = *(const float4*)&sbuf[bsel][l][0][lrd];
            const float4 yr = *(const float4*)&sbuf[bsel][l][1][lrd];
            const float m = rmask[r] * pm;
            float4 v = make_float4((xr.x - yr.x) * m, (xr.y - yr.y) * m,
                                   (xr.z - yr.z) * m, (xr.w - yr.w) * m);
            float Lm = __shfl_up(v.w, 1, 64);
            float Rp = __shfl_down(v.x, 1, 64);
            if (lane == 0) Lm = 0.f;           // w = -1 zero pad
            // lane 55's Rp comes from lane 56: v there is 0 (wact mask) ✓
            sw[r] = make_float4(Lm + 2.f * v.x + v.y,
                                v.x + 2.f * v.y + v.z,
                                v.y + 2.f * v.z + v.w,
                                v.z + 2.f * v.w + Rp);
            gw[r] = make_float4(Lm - v.y, v.x - v.z, v.y - v.w, v.z - Rp);
        }
        float4 n0[2], n1[2], n2[2];
        #pragma unroll
        for (int j = 0; j < 2; ++j) {
            n0[j] = make_float4(sw[j].x + 2.f * sw[j+1].x + sw[j+2].x,
                                sw[j].y + 2.f * sw[j+1].y + sw[j+2].y,
                                sw[j].z + 2.f * sw[j+1].z + sw[j+2].z,
                                sw[j].w + 2.f * sw[j+1].w + sw[j+2].w);  // s_h s_w
            n1[j] = make_float4(sw[j].x - sw[j+2].x, sw[j].y - sw[j+2].y,
                                sw[j].z - sw[j+2].z, sw[j].w - sw[j+2].w); // g_h s_w
            n2[j] = make_float4(gw[j].x + 2.f * gw[j+1].x + gw[j+2].x,
                                gw[j].y + 2.f * gw[j+1].y + gw[j+2].y,
                                gw[j].z + 2.f * gw[j+1].z + gw[j+2].z,
                                gw[j].w + 2.f * gw[j+1].w + gw[j+2].w);  // s_h g_w
        }

        // ---- d-combine for center plane q-1 (A = q-2, B = q-1, n = q) ----
        if (it >= 2 && wact) {
            #pragma unroll
            for (int j = 0; j < 2; ++j) {
                float4 gx = make_float4(A0[j].x - n0[j].x, A0[j].y - n0[j].y,
                                        A0[j].z - n0[j].z, A0[j].w - n0[j].w);
                float4 gy = make_float4(A1[j].x + 2.f * B1[j].x + n1[j].x,
                                        A1[j].y + 2.f * B1[j].y + n1[j].y,
                                        A1[j].z + 2.f * B1[j].z + n1[j].z,
                                        A1[j].w + 2.f * B1[j].w + n1[j].w);
                float4 gz = make_float4(A2[j].x + 2.f * B2[j].x + n2[j].x,
                                        A2[j].y + 2.f * B2[j].y + n2[j].y,
                                        A2[j].z + 2.f * B2[j].z + n2[j].z,
                                        A2[j].w + 2.f * B2[j].w + n2[j].w);
                acc = fmaf(gx.x, gx.x, acc); acc = fmaf(gx.y, gx.y, acc);
                acc = fmaf(gx.z, gx.z, acc); acc = fmaf(gx.w, gx.w, acc);
                acc = fmaf(gy.x, gy.x, acc); acc = fmaf(gy.y, gy.y, acc);
                acc = fmaf(gy.z, gy.z, acc); acc = fmaf(gy.w, gy.w, acc);
                acc = fmaf(gz.x, gz.x, acc); acc = fmaf(gz.y, gz.y, acc);
                acc = fmaf(gz.z, gz.z, acc); acc = fmaf(gz.w, gz.w, acc);
            }
        }

        // ---- rotate history ----
        #pragma unroll
        for (int j = 0; j < 2; ++j) {
            A0[j] = B0[j]; A1[j] = B1[j]; A2[j] = B2[j];
            B0[j] = n0[j]; B1[j] = n1[j]; B2[j] = n2[j];
        }
    }

    // ---- reduction: wave butterfly, LDS combine, one atomic per block ----
    #pragma unroll
    for (int off = 32; off > 0; off >>= 1)
        acc += __shfl_xor(acc, off, 64);
    if (lane == 0) wsum[wv] = acc;
    __syncthreads();
    if (tid == 0) {
        float s = (wsum[0] + wsum[1]) + (wsum[2] + wsum[3]);
        atomicAdd(out, s * SCALE);
    }
}

extern "C" void kernel_launch(void* const* d_in, const int* in_sizes, int n_in,
                              void* d_out, int out_size, void* d_ws, size_t ws_size,
                              hipStream_t stream) {
    const float* x = (const float*)d_in[0];
    const float* y = (const float*)d_in[1];
    float* out = (float*)d_out;

    hipMemsetAsync(out, 0, sizeof(float), stream);

    dim3 block(256);                    // 4 waves; one wave = full W x 2 h-rows
    dim3 grid(1,
              H_ / TH,                  // 24
              N_ * (D_ / TD));          // 20  -> 480 blocks, 4/CU resident
    grad_loss_kernel<<<grid, block, 0, stream>>>(x, y, out);
}

// Round 4
// 134.332 us; speedup vs baseline: 1.7992x; 1.7992x over previous
//
#include <hip/hip_runtime.h>
#include <stdint.h>

// GradientLoss: sum_c mean( (conv3d_c(x) - conv3d_c(y))^2 ), c in {d,h,w} Sobel dirs.
// conv linear -> conv(x)-conv(y) = conv(x-y). Separable: s=[1,2,1], g=[1,0,-1];
// SAME zero pad; squared output -> flip irrelevant.
//
// R13: NO LDS, NO BARRIERS — pure per-wave register streaming.
//  - R9-R11 (global_load_lds, all depths/grids): pegged at 45-52us, all pipes
//    ~20% -> the barrier-coupled DMA cadence is structural, not tunable.
//  - R12 (reg->LDS staging): launch_bounds(256,4) capped VGPR at 64 -> spill
//    (WRITE_SIZE 15KB -> 126MB). Lesson: give the allocator headroom.
//  - Insight: intra-block h-halo sharing only dedups SAME-CU re-reads, which
//    L1 serves anyway. LDS bought nothing; barriers coupled 4 waves to the
//    slowest load every plane. Drop both.
//  - Each wave: 2 output rows; per plane load 4 rows x {x,y} = 8 float4/lane
//    (global_load_dwordx4, rows are 896B contiguous), immediately reduce to
//    masked v=(x-y)*m (frees the 32-reg buffer -> single-buffer pipeline via
//    issue order), fold w/h stencils straight into n0/n1/n2 accumulators,
//    d-combine with 2-plane register history. No syncthreads in the loop.
//  - 12 waves/CU demand ~95 B/cy vs ~10 B/cy HBM supply -> HBM-bound regime;
//    wave drift smooths demand; L1/L2 absorb the 2x h-halo redundancy.
//  - launch_bounds(256,3): VGPR cap ~170 (est. use ~150, no spill),
//    TD=10 -> grid 24x32=768 = exactly 3 blocks/CU.

#define N_  2
#define D_  160
#define H_  192
#define W_  224
#define PS  (H_ * W_)

#define TD  10                 // d-planes per block (160/10 = 16 chunks)
#define TH  8                  // h output rows per block (2 per wave)
constexpr float SCALE = 1.0f / ((float)N_ * D_ * H_ * W_);

__device__ __forceinline__ float4 f4add(float4 a, float4 b) {
    return make_float4(a.x + b.x, a.y + b.y, a.z + b.z, a.w + b.w);
}
__device__ __forceinline__ float4 f4sub(float4 a, float4 b) {
    return make_float4(a.x - b.x, a.y - b.y, a.z - b.z, a.w - b.w);
}
__device__ __forceinline__ float4 f4fma(float k, float4 a, float4 b) {  // k*a + b
    return make_float4(fmaf(k, a.x, b.x), fmaf(k, a.y, b.y),
                       fmaf(k, a.z, b.z), fmaf(k, a.w, b.w));
}

__global__ __launch_bounds__(256, 3)
void grad_loss_kernel(const float* __restrict__ x, const float* __restrict__ y,
                      float* __restrict__ out) {
    __shared__ float wsum[4];

    const int tid  = threadIdx.x;
    const int lane = tid & 63;
    const int wv   = tid >> 6;

    const int nchunks = D_ / TD;               // 16
    const int nb = blockIdx.z / nchunks;
    const int d0 = (blockIdx.z % nchunks) * TD;
    const int h0w = blockIdx.y * TH + 2 * wv;  // this wave's first output row

    const float* vbx = x + (size_t)nb * ((size_t)D_ * PS);
    const float* vby = y + (size_t)nb * ((size_t)D_ * PS);

    // Per-lane row offsets (clamped) + masks. Lanes 56..63 duplicate lane 55's
    // 16B (same cache line, valid memory) and are zeroed by the mask.
    const bool wact = lane < 56;               // 56 lanes x 4 floats = 224 = W
    const int lo4c = (lane < 56 ? lane : 55) * 4;
    int off[4];
    float rmask[4];
    #pragma unroll
    for (int r = 0; r < 4; ++r) {
        int gh  = h0w - 1 + r;
        int ghc = min(max(gh, 0), H_ - 1);
        off[r]   = ghc * W_ + lo4c;
        rmask[r] = (((unsigned)gh < (unsigned)H_) && wact) ? 1.f : 0.f;
    }

    float4 XR[8];                              // current plane: 4 rows x {x,y}
    auto loadp = [&](int p) {
        int pc = min(max(p, 0), D_ - 1);       // clamp; masked via pm on use
        const float* bx = vbx + (size_t)pc * PS;
        const float* by = vby + (size_t)pc * PS;
        #pragma unroll
        for (int r = 0; r < 4; ++r) {
            XR[2 * r]     = *(const float4*)(bx + off[r]);
            XR[2 * r + 1] = *(const float4*)(by + off[r]);
        }
    };

    float4 A0[2], A1[2], A2[2], B0[2], B1[2], B2[2];   // d-history (q-2, q-1)
    const float4 z4 = make_float4(0.f, 0.f, 0.f, 0.f);
    #pragma unroll
    for (int j = 0; j < 2; ++j) { A0[j]=A1[j]=A2[j]=B0[j]=B1[j]=B2[j]=z4; }
    float acc = 0.f;

    loadp(d0 - 1);                             // prologue: first plane in flight

    for (int it = 0; it < TD + 2; ++it) {
        const int q = d0 - 1 + it;             // plane whose stencil we compute
        const float pm = (q >= 0 && q < D_) ? 1.f : 0.f;

        // ---- consume XR into masked diff rows (waits on the loads) ----
        float4 v[4];
        #pragma unroll
        for (int r = 0; r < 4; ++r) {
            const float m = rmask[r] * pm;
            v[r] = make_float4((XR[2*r].x - XR[2*r+1].x) * m,
                               (XR[2*r].y - XR[2*r+1].y) * m,
                               (XR[2*r].z - XR[2*r+1].z) * m,
                               (XR[2*r].w - XR[2*r+1].w) * m);
        }

        // ---- issue next plane's loads (XR free: WAR via issue order) ----
        if (it <= TD) loadp(d0 + it);          // skip final overshoot

        // ---- w-stencil per row, folded straight into h-stencil accums ----
        // n0 = s_h s_w, n1 = g_h s_w, n2 = s_h g_w  (2 output rows j=0,1)
        float4 n0[2], n1[2], n2[2];
        #pragma unroll
        for (int r = 0; r < 4; ++r) {
            const float4 vv = v[r];
            float Lm = __shfl_up(vv.w, 1, 64);
            float Rp = __shfl_down(vv.x, 1, 64);
            if (lane == 0) Lm = 0.f;           // w = -1 zero pad
            // lane 55's Rp comes from lane 56: v there is 0 (mask) ✓
            const float4 s = make_float4(Lm + 2.f * vv.x + vv.y,
                                         vv.x + 2.f * vv.y + vv.z,
                                         vv.y + 2.f * vv.z + vv.w,
                                         vv.z + 2.f * vv.w + Rp);
            const float4 g = make_float4(Lm - vv.y, vv.x - vv.z,
                                         vv.y - vv.w, vv.z - Rp);
            if (r == 0) { n0[0] = s;                 n1[0] = s;
                          n2[0] = g; }
            if (r == 1) { n0[0] = f4fma(2.f, s, n0[0]);
                          n2[0] = f4fma(2.f, g, n2[0]);
                          n0[1] = s;                 n1[1] = s;
                          n2[1] = g; }
            if (r == 2) { n0[0] = f4add(n0[0], s);   n1[0] = f4sub(n1[0], s);
                          n2[0] = f4add(n2[0], g);
                          n0[1] = f4fma(2.f, s, n0[1]);
                          n2[1] = f4fma(2.f, g, n2[1]); }
            if (r == 3) { n0[1] = f4add(n0[1], s);   n1[1] = f4sub(n1[1], s);
                          n2[1] = f4add(n2[1], g); }
        }

        // ---- d-combine for center plane q-1 (A = q-2, B = q-1, n = q) ----
        if (it >= 2) {
            #pragma unroll
            for (int j = 0; j < 2; ++j) {
                const float4 gx = f4sub(A0[j], n0[j]);                 // g_d s_h s_w
                const float4 gy = f4add(f4fma(2.f, B1[j], A1[j]), n1[j]); // s_d g_h s_w
                const float4 gz = f4add(f4fma(2.f, B2[j], A2[j]), n2[j]); // s_d s_h g_w
                acc = fmaf(gx.x, gx.x, acc); acc = fmaf(gx.y, gx.y, acc);
                acc = fmaf(gx.z, gx.z, acc); acc = fmaf(gx.w, gx.w, acc);
                acc = fmaf(gy.x, gy.x, acc); acc = fmaf(gy.y, gy.y, acc);
                acc = fmaf(gy.z, gy.z, acc); acc = fmaf(gy.w, gy.w, acc);
                acc = fmaf(gz.x, gz.x, acc); acc = fmaf(gz.y, gz.y, acc);
                acc = fmaf(gz.z, gz.z, acc); acc = fmaf(gz.w, gz.w, acc);
            }
        }

        // ---- rotate history ----
        #pragma unroll
        for (int j = 0; j < 2; ++j) {
            A0[j] = B0[j]; A1[j] = B1[j]; A2[j] = B2[j];
            B0[j] = n0[j]; B1[j] = n1[j]; B2[j] = n2[j];
        }
    }

    // ---- reduction: wave butterfly, LDS combine, one atomic per block ----
    #pragma unroll
    for (int off_ = 32; off_ > 0; off_ >>= 1)
        acc += __shfl_xor(acc, off_, 64);
    if (lane == 0) wsum[wv] = acc;
    __syncthreads();
    if (tid == 0) {
        float s = (wsum[0] + wsum[1]) + (wsum[2] + wsum[3]);
        atomicAdd(out, s * SCALE);
    }
}

extern "C" void kernel_launch(void* const* d_in, const int* in_sizes, int n_in,
                              void* d_out, int out_size, void* d_ws, size_t ws_size,
                              hipStream_t stream) {
    const float* x = (const float*)d_in[0];
    const float* y = (const float*)d_in[1];
    float* out = (float*)d_out;

    hipMemsetAsync(out, 0, sizeof(float), stream);

    dim3 block(256);                    // 4 independent waves; no intra-loop sync
    dim3 grid(1,
              H_ / TH,                  // 24
              N_ * (D_ / TD));          // 32  -> 768 blocks = 3 blocks/CU
    grad_loss_kernel<<<grid, block, 0, stream>>>(x, y, out);
}

// Round 5
// 133.723 us; speedup vs baseline: 1.8074x; 1.0046x over previous
//
#include <hip/hip_runtime.h>
#include <stdint.h>

// GradientLoss: sum_c mean( (conv3d_c(x) - conv3d_c(y))^2 ), c in {d,h,w} Sobel dirs.
// conv linear -> conv(x)-conv(y) = conv(x-y). Separable: s=[1,2,1], g=[1,0,-1];
// SAME zero pad; squared output -> flip irrelevant.
//
// R14 = R13 (pure-register streaming, no LDS/barriers) with WIDER h-tile.
//  - R13 post-mortem: 44.8us, VALU=HBM=22%, FETCH 79MB, no spill. Demand-side
//    roofline: 264 MB L1-demand / 45us = 5.9 TB/s, vs harness fill kernel at
//    6.55 TB/s on the same run -> R13 is ~90% of achievable memory-system
//    throughput FOR ITS DEMAND STREAM. Bound by demand bytes, not HBM bytes.
//  - Lever: cut redundancy. R13 = h-halo 2.0x * d-halo 1.2x = 2.4x.
//    R14: RW=4 rows/wave (load 6 rows/plane) -> 1.5x * 1.2x = 1.8x
//    -> demand 198 MB (-25%). Predicted ~34-37us if demand-BW-bound.
//  - 128-thread blocks (2 waves x 4 rows = TH 8) keep grid at 768 blocks.
//    VGPR ~225 (XR 48 + hist 96 + n 48 + misc) -> launch_bounds(128,2),
//    cap 256, no spill (R12 lesson: check WRITE_SIZE stays KB).
//  - Restored wact guard on accumulation (R13 leaked lane55's Lm into lane 56
//    via shfl_up; small systematic error hidden by tolerance).

#define N_  2
#define D_  160
#define H_  192
#define W_  224
#define PS  (H_ * W_)

#define TD  10                 // d-planes per block (160/10 = 16 chunks)
#define RW  4                  // output rows per wave
#define TH  8                  // rows per block = 2 waves x RW
constexpr float SCALE = 1.0f / ((float)N_ * D_ * H_ * W_);

__device__ __forceinline__ float4 f4add(float4 a, float4 b) {
    return make_float4(a.x + b.x, a.y + b.y, a.z + b.z, a.w + b.w);
}
__device__ __forceinline__ float4 f4sub(float4 a, float4 b) {
    return make_float4(a.x - b.x, a.y - b.y, a.z - b.z, a.w - b.w);
}
__device__ __forceinline__ float4 f4fma(float k, float4 a, float4 b) {  // k*a + b
    return make_float4(fmaf(k, a.x, b.x), fmaf(k, a.y, b.y),
                       fmaf(k, a.z, b.z), fmaf(k, a.w, b.w));
}

__global__ __launch_bounds__(128, 2)
void grad_loss_kernel(const float* __restrict__ x, const float* __restrict__ y,
                      float* __restrict__ out) {
    __shared__ float wsum[2];

    const int tid  = threadIdx.x;
    const int lane = tid & 63;
    const int wv   = tid >> 6;                 // 0..1

    const int nchunks = D_ / TD;               // 16
    const int nb = blockIdx.z / nchunks;
    const int d0 = (blockIdx.z % nchunks) * TD;
    const int h0w = blockIdx.y * TH + RW * wv; // this wave's first output row

    const float* vbx = x + (size_t)nb * ((size_t)D_ * PS);
    const float* vby = y + (size_t)nb * ((size_t)D_ * PS);

    // Per-lane row offsets (clamped) + masks. Lanes 56..63 duplicate lane 55's
    // 16B (same cache line, valid memory) and are zeroed by the mask.
    const bool wact = lane < 56;               // 56 lanes x 4 floats = 224 = W
    const int lo4c = (lane < 56 ? lane : 55) * 4;
    int off[6];
    float rmask[6];
    #pragma unroll
    for (int r = 0; r < 6; ++r) {              // loaded rows h0w-1 .. h0w+4
        int gh  = h0w - 1 + r;
        int ghc = min(max(gh, 0), H_ - 1);
        off[r]   = ghc * W_ + lo4c;
        rmask[r] = (((unsigned)gh < (unsigned)H_) && wact) ? 1.f : 0.f;
    }

    float4 XR[12];                             // current plane: 6 rows x {x,y}
    auto loadp = [&](int p) {
        int pc = min(max(p, 0), D_ - 1);       // clamp; masked via pm on use
        const float* bx = vbx + (size_t)pc * PS;
        const float* by = vby + (size_t)pc * PS;
        #pragma unroll
        for (int r = 0; r < 6; ++r) {
            XR[2 * r]     = *(const float4*)(bx + off[r]);
            XR[2 * r + 1] = *(const float4*)(by + off[r]);
        }
    };

    float4 A0[RW], A1[RW], A2[RW], B0[RW], B1[RW], B2[RW];  // d-hist (q-2,q-1)
    const float4 z4 = make_float4(0.f, 0.f, 0.f, 0.f);
    #pragma unroll
    for (int j = 0; j < RW; ++j) { A0[j]=A1[j]=A2[j]=B0[j]=B1[j]=B2[j]=z4; }
    float acc = 0.f;

    loadp(d0 - 1);                             // prologue: first plane in flight

    for (int it = 0; it < TD + 2; ++it) {
        const int q = d0 - 1 + it;             // plane whose stencil we compute
        const float pm = (q >= 0 && q < D_) ? 1.f : 0.f;

        // ---- consume XR row-by-row, fold straight into n accumulators ----
        // n0 = s_h s_w, n1 = g_h s_w, n2 = s_h g_w for output rows j=0..3;
        // output row j uses loaded rows r = j, j+1, j+2.
        float4 n0[RW], n1[RW], n2[RW];
        #pragma unroll
        for (int r = 0; r < 6; ++r) {
            const float m = rmask[r] * pm;
            const float4 vv = make_float4((XR[2*r].x - XR[2*r+1].x) * m,
                                          (XR[2*r].y - XR[2*r+1].y) * m,
                                          (XR[2*r].z - XR[2*r+1].z) * m,
                                          (XR[2*r].w - XR[2*r+1].w) * m);
            float Lm = __shfl_up(vv.w, 1, 64);
            float Rp = __shfl_down(vv.x, 1, 64);
            if (lane == 0) Lm = 0.f;           // w = -1 zero pad
            // lane 55's Rp comes from lane 56: vv there is 0 (mask) ✓
            const float4 s = make_float4(Lm + 2.f * vv.x + vv.y,
                                         vv.x + 2.f * vv.y + vv.z,
                                         vv.y + 2.f * vv.z + vv.w,
                                         vv.z + 2.f * vv.w + Rp);
            const float4 g = make_float4(Lm - vv.y, vv.x - vv.z,
                                         vv.y - vv.w, vv.z - Rp);
            #pragma unroll
            for (int j = 0; j < RW; ++j) {
                if (r == j) {                  // first contribution: assign
                    n0[j] = s; n1[j] = s; n2[j] = g;
                } else if (r == j + 1) {       // center row, weight 2 (s only)
                    n0[j] = f4fma(2.f, s, n0[j]);
                    n2[j] = f4fma(2.f, g, n2[j]);
                } else if (r == j + 2) {       // bottom row
                    n0[j] = f4add(n0[j], s);
                    n1[j] = f4sub(n1[j], s);
                    n2[j] = f4add(n2[j], g);
                }
            }
        }

        // ---- issue next plane's loads (XR free: WAR via issue order) ----
        if (it <= TD) loadp(d0 + it);          // skip final overshoot

        // ---- d-combine for center plane q-1 (A = q-2, B = q-1, n = q) ----
        if (it >= 2 && wact) {
            #pragma unroll
            for (int j = 0; j < RW; ++j) {
                const float4 gx = f4sub(A0[j], n0[j]);                    // g_d s_h s_w
                const float4 gy = f4add(f4fma(2.f, B1[j], A1[j]), n1[j]); // s_d g_h s_w
                const float4 gz = f4add(f4fma(2.f, B2[j], A2[j]), n2[j]); // s_d s_h g_w
                acc = fmaf(gx.x, gx.x, acc); acc = fmaf(gx.y, gx.y, acc);
                acc = fmaf(gx.z, gx.z, acc); acc = fmaf(gx.w, gx.w, acc);
                acc = fmaf(gy.x, gy.x, acc); acc = fmaf(gy.y, gy.y, acc);
                acc = fmaf(gy.z, gy.z, acc); acc = fmaf(gy.w, gy.w, acc);
                acc = fmaf(gz.x, gz.x, acc); acc = fmaf(gz.y, gz.y, acc);
                acc = fmaf(gz.z, gz.z, acc); acc = fmaf(gz.w, gz.w, acc);
            }
        }

        // ---- rotate history ----
        #pragma unroll
        for (int j = 0; j < RW; ++j) {
            A0[j] = B0[j]; A1[j] = B1[j]; A2[j] = B2[j];
            B0[j] = n0[j]; B1[j] = n1[j]; B2[j] = n2[j];
        }
    }

    // ---- reduction: wave butterfly, LDS combine, one atomic per block ----
    #pragma unroll
    for (int off_ = 32; off_ > 0; off_ >>= 1)
        acc += __shfl_xor(acc, off_, 64);
    if (lane == 0) wsum[wv] = acc;
    __syncthreads();
    if (tid == 0) {
        atomicAdd(out, (wsum[0] + wsum[1]) * SCALE);
    }
}

extern "C" void kernel_launch(void* const* d_in, const int* in_sizes, int n_in,
                              void* d_out, int out_size, void* d_ws, size_t ws_size,
                              hipStream_t stream) {
    const float* x = (const float*)d_in[0];
    const float* y = (const float*)d_in[1];
    float* out = (float*)d_out;

    hipMemsetAsync(out, 0, sizeof(float), stream);

    dim3 block(128);                    // 2 independent waves; no intra-loop sync
    dim3 grid(1,
              H_ / TH,                  // 24
              N_ * (D_ / TD));          // 32  -> 768 blocks
    grad_loss_kernel<<<grid, block, 0, stream>>>(x, y, out);
}